// Round 19
// baseline (87.985 us; speedup 1.0000x reference)
//
#include <hip/hip_runtime.h>
#include <hip/hip_bf16.h>

// Problem constants: B=4, S=512, N=2048, E=1024, QL=32, H=8, D=2, VL=32
// Inputs: 0 embeddings[4,512,1024] 1 keys[4,2048,256] 2 values[4,2048,256]
//         3 ocs[8,1024,2048] 4 Wq[512,1024] 5 bq[512] 6 Wo[1024,512] 7 bo[1024]
//         8 gamma[512] 9 beta[512]       all float32.  Output [4,512,1024] f32.

typedef short  short8 __attribute__((ext_vector_type(8)));
typedef float  f32x4  __attribute__((ext_vector_type(4)));

__device__ __forceinline__ ushort f2bf(float x) {
  union { float f; unsigned int u; } v; v.f = x;
  unsigned int r = v.u + 0x7fffu + ((v.u >> 16) & 1u);
  return (ushort)(r >> 16);
}

// hardware packed f32x2 -> bf16x2 (RNE), 1 instr. Used ONLY where the
// consumer is a DS/shuffle/store op (never directly feeding MFMA).
__device__ __forceinline__ unsigned int cvtpk(float a, float b) {
  unsigned int r;
  asm("v_cvt_pk_bf16_f32 %0, %1, %2" : "=v"(r) : "v"(a), "v"(b));
  return r;
}
__device__ __forceinline__ short8 cvt8(f32x4 a, f32x4 b) {
  union { unsigned int u[4]; short8 s; } r;
  r.u[0] = cvtpk(a[0], a[1]);
  r.u[1] = cvtpk(a[2], a[3]);
  r.u[2] = cvtpk(b[0], b[1]);
  r.u[3] = cvtpk(b[2], b[3]);
  return r.s;
}

#if __has_builtin(__builtin_amdgcn_global_load_lds)
#define OCS_ASYNC 1
__device__ __forceinline__ void gl_lds16(const float* g, float* l) {
  __builtin_amdgcn_global_load_lds(
      (const __attribute__((address_space(1))) unsigned int*)g,
      (__attribute__((address_space(3))) unsigned int*)l, 16, 0, 0);
}
#else
#define OCS_ASYNC 0
#endif

// ---------------------------------------------------------------------------
// prep body: keys[b,n,ql*8+h] -> kbf[b,h,n',ql] (permuted tiles: position
// p = 16s+4gg+r holds source row 8gg+4s+r, so QK^T output lands directly in
// the K=32 PV B-fragment order); values -> vbf[b,h,vl,n].
// ---------------------------------------------------------------------------
__device__ __forceinline__ void prep_body(
    char* smem, int bi,
    const float* __restrict__ keys, const float* __restrict__ values,
    ushort* __restrict__ kbf, ushort* __restrict__ vbf)
{
  ushort (*T)[264] = (ushort (*)[264])smem;    // [32][264]
  const int b  = bi >> 6;
  const int n0 = (bi & 63) * 32;
  const int t  = threadIdx.x;
  const int nr = t >> 3;                // 0..31
  const int c0 = (t & 7) * 32;          // 0..224

  {
    const float* src = keys + ((size_t)b*2048 + n0 + nr)*256 + c0;
#pragma unroll
    for (int j = 0; j < 32; j += 8) {
      f32x4 x0 = *(const f32x4*)(src + j);
      f32x4 x1 = *(const f32x4*)(src + j + 4);
      *(short8*)&T[nr][c0 + j] = cvt8(x0, x1);
    }
  }
  __syncthreads();
  {
    const int h = t >> 5, nn = t & 31;
    const int pp = 16*((nn >> 2) & 1) + 4*(nn >> 3) + (nn & 3);
    ushort* dst = kbf + (((size_t)(b*8 + h) * 2048) + n0 + pp) * 32;
#pragma unroll
    for (int j = 0; j < 4; j++) {
      short8 w;
#pragma unroll
      for (int i = 0; i < 8; i++) w[i] = (short)T[nn][(j*8 + i)*8 + h];
      *(short8*)(dst + j*8) = w;
    }
  }
  __syncthreads();
  {
    const float* src = values + ((size_t)b*2048 + n0 + nr)*256 + c0;
#pragma unroll
    for (int j = 0; j < 32; j += 8) {
      f32x4 x0 = *(const f32x4*)(src + j);
      f32x4 x1 = *(const f32x4*)(src + j + 4);
      *(short8*)&T[nr][c0 + j] = cvt8(x0, x1);
    }
  }
  __syncthreads();
  {
    const int c = t, h = c & 7, vl = c >> 3;
    ushort* dst = vbf + (((size_t)(b*8 + h) * 32) + vl) * 2048 + n0;
#pragma unroll
    for (int j = 0; j < 4; j++) {
      short8 w;
#pragma unroll
      for (int i = 0; i < 8; i++) w[i] = (short)T[j*8 + i][c];
      *(short8*)(dst + j*8) = w;
    }
  }
}

// ---------------------------------------------------------------------------
// GEMM body (NT): out[m,n] = sum_k A'[m,k]*B[n,k] + bias[n]. 64x64 tile,
// 4 waves, R15-proven pipeline: double-buffered LDS, prefetch distance 1,
// raw s_barrier (no vmcnt drain), lgkmcnt(0) before write-side barrier.
// EPI=0: A'=A; scatter-store bf16*(1/sqrt32) into qbf.
// EPI=1: A'[m,k] = (A[m,k]-mean[m])*rstd[m]*gamma[k]+beta[k], stats from
//        per-row sum/sumsq (combine's atomics); f32 row-major out.
// ---------------------------------------------------------------------------
template<int EPI>
__device__ __forceinline__ void gemm_body(
    char* smem,
    const float* __restrict__ A, const float* __restrict__ Bm,
    const float* __restrict__ bias, void* __restrict__ outp,
    int M, int N, int K, int m0, int n0,
    const float* __restrict__ rowsum, const float* __restrict__ rowsumsq,
    const float* __restrict__ gamma,  const float* __restrict__ beta)
{
  ushort* As = (ushort*)smem;            // [2][64][32]
  ushort* Bs = (ushort*)(smem + 8192);   // [2][64][32]
  const int tid = threadIdx.x;
  const int lane = tid & 63;
  const int wid  = tid >> 6;
  const int wm = wid >> 1, wn = wid & 1;
  const int lt = lane & 15, g = lane >> 4;
  const int lrow = tid >> 2;      // 0..63
  const int lseg = tid & 3;       // 0..3 (8 floats each)
  const int slot_w = lseg ^ ((lrow & 3) ^ ((lrow >> 2) & 3));

  f32x4 acc[2][2] = {};
  f32x4 pa0, pa1, pb0, pb1;     // named prefetch registers

  float mean_r = 0.f, rstd_r = 1.f;
  if (EPI == 1) {
    const float s_  = rowsum[m0 + lrow];
    const float sq_ = rowsumsq[m0 + lrow];
    mean_r = s_ * (1.0f/512.0f);
    rstd_r = rsqrtf(sq_ * (1.0f/512.0f) - mean_r * mean_r + 1e-5f);
  }

#define GLOAD(K0) do {                                                        \
    const float* sa_ = A  + (size_t)(m0 + lrow) * K + (K0) + lseg * 8;        \
    pa0 = *(const f32x4*)sa_;  pa1 = *(const f32x4*)(sa_ + 4);                \
    const float* sb_ = Bm + (size_t)(n0 + lrow) * K + (K0) + lseg * 8;        \
    pb0 = *(const f32x4*)sb_;  pb1 = *(const f32x4*)(sb_ + 4);                \
  } while (0)
#define SWRITE(BUF, K0) do {                                                  \
    f32x4 qa0 = pa0, qa1 = pa1;                                               \
    if (EPI == 1) {                                                           \
      const float* gp_ = gamma + (K0) + lseg * 8;                             \
      const float* bp_ = beta  + (K0) + lseg * 8;                             \
      f32x4 g0_ = *(const f32x4*)gp_, g1_ = *(const f32x4*)(gp_ + 4);         \
      f32x4 b0_ = *(const f32x4*)bp_, b1_ = *(const f32x4*)(bp_ + 4);         \
      _Pragma("unroll")                                                       \
      for (int r_ = 0; r_ < 4; r_++) {                                        \
        qa0[r_] = (qa0[r_] - mean_r) * rstd_r * g0_[r_] + b0_[r_];            \
        qa1[r_] = (qa1[r_] - mean_r) * rstd_r * g1_[r_] + b1_[r_];            \
      }                                                                       \
    }                                                                         \
    *(short8*)&As[(BUF)*2048 + lrow*32 + slot_w * 8] = cvt8(qa0, qa1);        \
    *(short8*)&Bs[(BUF)*2048 + lrow*32 + slot_w * 8] = cvt8(pb0, pb1);        \
  } while (0)

  // prologue: stage k=0 into buf 0 (full drain once is fine)
  GLOAD(0);
  SWRITE(0, 0);
  __syncthreads();

  int cur = 0;
  for (int k0 = 0; k0 < K; k0 += 32) {
    const bool more = (k0 + 32 < K);
    if (more) GLOAD(k0 + 32);          // in flight across barrier1
    short8 af[2], bfr[2];
#pragma unroll
    for (int ss = 0; ss < 2; ss++) {
      const int ra = wm*32 + ss*16 + lt;
      af[ss]  = *(const short8*)&As[cur*2048 + ra*32 + (g ^ ((ra & 3) ^ ((ra >> 2) & 3))) * 8];
      const int rb = wn*32 + ss*16 + lt;
      bfr[ss] = *(const short8*)&Bs[cur*2048 + rb*32 + (g ^ ((rb & 3) ^ ((rb >> 2) & 3))) * 8];
    }
#pragma unroll
    for (int i = 0; i < 2; i++)
#pragma unroll
      for (int j = 0; j < 2; j++)
        acc[i][j] = __builtin_amdgcn_mfma_f32_16x16x32_bf16(af[i], bfr[j], acc[i][j], 0, 0, 0);
    asm volatile("s_barrier" ::: "memory");
    if (more) {
      SWRITE(cur ^ 1, k0 + 32);
      asm volatile("s_waitcnt lgkmcnt(0)" ::: "memory");
    }
    asm volatile("s_barrier" ::: "memory");
    cur ^= 1;
  }

#pragma unroll
  for (int i = 0; i < 2; i++)
#pragma unroll
    for (int j = 0; j < 2; j++) {
      const int n  = n0 + wn*32 + j*16 + lt;
      const float bv = bias[n];
      const int mb = m0 + wm*32 + i*16 + g*4;
#pragma unroll
      for (int r = 0; r < 4; r++) {
        const int mm = mb + r;
        if (EPI == 0) {
          const float val = (acc[i][j][r] + bv) * 0.17677669529663687f;
          const int bb = mm >> 9, s = mm & 511;
          const int d = n >> 8, ql = (n >> 3) & 31, hh = n & 7;
          const int tt = s*2 + d;
          ((ushort*)outp)[((size_t)(bb*8 + hh) * 1024 + tt) * 32 + ql] = f2bf(val);
        } else {
          ((float*)outp)[(size_t)mm * N + n] = acc[i][j][r] + bv;
        }
      }
    }
#undef GLOAD
#undef SWRITE
}

// ---------------------------------------------------------------------------
// Fused dispatch 1: blocks 0..255 prep; 256..511 gemm0; 512..515 zero the
// LN stats accumulators (replaces a hipMemsetAsync graph node).
// ---------------------------------------------------------------------------
__global__ __launch_bounds__(256) void prep_gemm0(
    const float* __restrict__ keys, const float* __restrict__ values,
    ushort* __restrict__ kbf, ushort* __restrict__ vbf,
    const float* __restrict__ emb, const float* __restrict__ Wq,
    const float* __restrict__ bq, ushort* __restrict__ qbf,
    float* __restrict__ stats)   // 4096 floats: rsum[2048] ++ rsq[2048]
{
  __shared__ __align__(16) char smem[17408];
  const int bi = blockIdx.x;
  if (bi < 256) {
    prep_body(smem, bi, keys, values, kbf, vbf);
  } else if (bi < 512) {
    const int gblk = bi - 256;           // 0..255 -> (mt 0..31, nt 0..7)
    const int m0 = (gblk & 31) * 64;
    const int n0 = (gblk >> 5) * 64;
    gemm_body<0>(smem, emb, Wq, bq, (void*)qbf, 2048, 512, 1024, m0, n0,
                 nullptr, nullptr, nullptr, nullptr);
  } else {
    stats[(bi - 512) * 1024 + threadIdx.x * 4 + 0] = 0.f;
    stats[(bi - 512) * 1024 + threadIdx.x * 4 + 1] = 0.f;
    stats[(bi - 512) * 1024 + threadIdx.x * 4 + 2] = 0.f;
    stats[(bi - 512) * 1024 + threadIdx.x * 4 + 3] = 0.f;
  }
}

// ---------------------------------------------------------------------------
// gemm1 with fused LayerNorm on A (stats derived from combine's atomics).
// ---------------------------------------------------------------------------
__global__ __launch_bounds__(256) void gemm1_ln(
    const float* __restrict__ vo, const float* __restrict__ Wo,
    const float* __restrict__ bo, float* __restrict__ outp,
    const float* __restrict__ rowsum, const float* __restrict__ rowsumsq,
    const float* __restrict__ gamma, const float* __restrict__ beta)
{
  __shared__ __align__(16) char smem[16384];
  gemm_body<1>(smem, vo, Wo, bo, (void*)outp, 2048, 1024, 512,
               blockIdx.x * 64, blockIdx.y * 64, rowsum, rowsumsq, gamma, beta);
}

// ---------------------------------------------------------------------------
// Attention (split-n), t-PAIR per wave, compile-time NSTEPS (static loop,
// static NSX). R14/R17 schedule otherwise byte-identical: 4-buffer LDS ocs
// ring, per pair [4 DMA then 8 K/V] pinned, pair-end vmcnt(8). s_setprio(1)
// wraps the MFMA/exp cluster (T5 hint).
// ---------------------------------------------------------------------------
template<int NSTEPS>
__global__ __launch_bounds__(256) void attn_kernel(
    const ushort* __restrict__ qbf, const ushort* __restrict__ kbf,
    const ushort* __restrict__ vbf, const float* __restrict__ ocs,
    float* __restrict__ pacc, float* __restrict__ pl)
{
#if OCS_ASYNC
  __shared__ float obuf[4][2048];   // ring: 4 x [2 tiles][32 rows][8 slots][4 f32]
#endif
  const int tid  = threadIdx.x;
  const int lane = tid & 63;
  const int id = blockIdx.x;
  const int h   = id & 7;
  const int ttp = (id >> 3) & 15;
  const int c   = id >> 7;
  const int b  = tid >> 6;
  const int wid0 = ((h << 5) + 2*ttp) * 4 + b;   // tile0's wid; tile1 = wid0+4
  const int t0 = ttp * 64;
  const int lt = lane & 15, g = lane >> 4;
  const int n_start = c * NSTEPS * 32;

  const ushort* qp = qbf + (size_t)(b*8 + h) * (1024*32);
  const ushort* kp = kbf + (size_t)(b*8 + h) * (2048*32);
  const ushort* vp = vbf + (size_t)(b*8 + h) * (32*2048);
  const float*  op = ocs + (size_t)h * (1024*2048);

#define NSX(I) (((I) < NSTEPS) ? (n_start + (I)*32) : n_start)

  const int srow = tid >> 3;
  const int scol = 4 * ((tid & 7) ^ (srow & 7));
  const float* sb0 = op + (size_t)(t0 + srow) * 2048 + scol;
  const float* sb1 = op + (size_t)(t0 + 32 + srow) * 2048 + scol;
#if OCS_ASYNC
  const int ldsw = (tid & 192) * 16;   // per-wave LDS byte base (lane*16 added by HW)
#define SL_ISSUE(STEP) do {                                                   \
    gl_lds16(sb0 + NSX(STEP), (float*)((char*)obuf + (((STEP) & 3) << 13) + ldsw));        \
    gl_lds16(sb1 + NSX(STEP), (float*)((char*)obuf + (((STEP) & 3) << 13) + 4096 + ldsw)); \
  } while (0)
  const int ro0 = lt * 128;            // ts=0 row byte offset
  const int ro1 = (16 + lt) * 128;     // ts=1
  const int c0x = ((2*g)     ^ (lt & 7)) * 16;   // sc0 slot bytes
  const int c1x = ((2*g + 1) ^ (lt & 7)) * 16;   // sc1 slot bytes
#define CO_READ(DST, TILE, STEP) do {                                         \
    const char* bb_ = (const char*)obuf + (((STEP) & 3) << 13) + ((TILE) << 12); \
    DST[0][0] = *(const f32x4*)(bb_ + ro0 + c0x);                             \
    DST[1][0] = *(const f32x4*)(bb_ + ro0 + c1x);                             \
    DST[0][1] = *(const f32x4*)(bb_ + ro1 + c0x);                             \
    DST[1][1] = *(const f32x4*)(bb_ + ro1 + c1x);                             \
  } while (0)
#define PAIR_SYNC() do {                                                      \
    __builtin_amdgcn_sched_barrier(0);                                        \
    asm volatile("s_waitcnt vmcnt(8)" ::: "memory");                          \
    __builtin_amdgcn_sched_barrier(0);                                        \
    __builtin_amdgcn_s_barrier();                                             \
  } while (0)
#else
#define SL_ISSUE(STEP)
#define CO_READ(DST, TILE, STEP) do {                                         \
    const int nn_ = NSX(STEP);                                                \
    const float* r0_ = op + (size_t)(t0 + (TILE)*32 + lt) * 2048 + nn_;       \
    const float* r1_ = op + (size_t)(t0 + (TILE)*32 + 16 + lt) * 2048 + nn_;  \
    DST[0][0] = *(const f32x4*)(r0_ + 8*g);                                   \
    DST[1][0] = *(const f32x4*)(r0_ + 8*g + 4);                               \
    DST[0][1] = *(const f32x4*)(r1_ + 8*g);                                   \
    DST[1][1] = *(const f32x4*)(r1_ + 8*g + 4);                               \
  } while (0)
#define PAIR_SYNC()
#endif

#define LD_KV(KD, VD, NN) do {                                                \
    KD[0] = *(const short8*)(kp + (size_t)((NN) + lt) * 32 + g*8);            \
    KD[1] = *(const short8*)(kp + (size_t)((NN) + 16 + lt) * 32 + g*8);       \
    VD[0] = *(const short8*)(vp + (size_t)lt * 2048 + (NN) + g*8);            \
    VD[1] = *(const short8*)(vp + (size_t)(16 + lt) * 2048 + (NN) + g*8);     \
  } while (0)

  short8 qf0[2], qf1[2];
#pragma unroll
  for (int ts = 0; ts < 2; ts++) {
    qf0[ts] = *(const short8*)(qp + (t0 + ts*16 + lt)*32 + g*8);
    qf1[ts] = *(const short8*)(qp + (t0 + 32 + ts*16 + lt)*32 + g*8);
  }

  f32x4 acc0[2][2] = {}, acc1[2][2] = {};
  float lsum0[2] = {0.f, 0.f}, lsum1[2] = {0.f, 0.f};
  const f32x4 fzero = {0.f, 0.f, 0.f, 0.f};

#define TSB(SC0, SC1, CO0, CO1, VLO, VHI, LS, ACCA, ACCB) do {                \
    float p0 = __expf(SC0[0] - CO0[0]);                                       \
    float p1 = __expf(SC0[1] - CO0[1]);                                       \
    float p2 = __expf(SC0[2] - CO0[2]);                                       \
    float p3 = __expf(SC0[3] - CO0[3]);                                       \
    float p4 = __expf(SC1[0] - CO1[0]);                                       \
    float p5 = __expf(SC1[1] - CO1[1]);                                       \
    float p6 = __expf(SC1[2] - CO1[2]);                                       \
    float p7 = __expf(SC1[3] - CO1[3]);                                       \
    LS += ((p0+p1)+(p2+p3)) + ((p4+p5)+(p6+p7));                              \
    union { unsigned int u[4]; short8 s; } pf;                                \
    pf.u[0] = (unsigned int)f2bf(p0) | ((unsigned int)f2bf(p1) << 16);        \
    pf.u[1] = (unsigned int)f2bf(p2) | ((unsigned int)f2bf(p3) << 16);        \
    pf.u[2] = (unsigned int)f2bf(p4) | ((unsigned int)f2bf(p5) << 16);        \
    pf.u[3] = (unsigned int)f2bf(p6) | ((unsigned int)f2bf(p7) << 16);        \
    ACCA = __builtin_amdgcn_mfma_f32_16x16x32_bf16(VLO, pf.s, ACCA, 0, 0, 0); \
    ACCB = __builtin_amdgcn_mfma_f32_16x16x32_bf16(VHI, pf.s, ACCB, 0, 0, 0); \
  } while (0)

#define STEPTILE(KC_, VC_, QFA, QFB, TILE, STEP, ACC, LS) do {                \
    f32x4 s0a = __builtin_amdgcn_mfma_f32_16x16x32_bf16(KC_[0], QFA, fzero, 0, 0, 0); \
    f32x4 s1a = __builtin_amdgcn_mfma_f32_16x16x32_bf16(KC_[1], QFA, fzero, 0, 0, 0); \
    f32x4 s0b = __builtin_amdgcn_mfma_f32_16x16x32_bf16(KC_[0], QFB, fzero, 0, 0, 0); \
    f32x4 s1b = __builtin_amdgcn_mfma_f32_16x16x32_bf16(KC_[1], QFB, fzero, 0, 0, 0); \
    f32x4 co[2][2];                                                           \
    CO_READ(co, TILE, STEP);                                                  \
    TSB(s0a, s1a, co[0][0], co[1][0], VC_[0], VC_[1], LS[0], ACC[0][0], ACC[0][1]); \
    TSB(s0b, s1b, co[0][1], co[1][1], VC_[0], VC_[1], LS[1], ACC[1][0], ACC[1][1]); \
  } while (0)

#define PAIR(SA_, KC, VC, KN, VN) do {                                        \
    const int sA_ = (SA_);                                                    \
    SL_ISSUE(sA_ + 2);                                                        \
    SL_ISSUE(sA_ + 3);                                                        \
    __builtin_amdgcn_sched_barrier(0);                                        \
    LD_KV(KN[0], VN[0], NSX(sA_ + 2));                                        \
    LD_KV(KN[1], VN[1], NSX(sA_ + 3));                                        \
    __builtin_amdgcn_sched_barrier(0);                                        \
    __builtin_amdgcn_s_setprio(1);                                            \
    STEPTILE(KC[0], VC[0], qf0[0], qf0[1], 0, sA_,     acc0, lsum0);          \
    STEPTILE(KC[0], VC[0], qf1[0], qf1[1], 1, sA_,     acc1, lsum1);          \
    STEPTILE(KC[1], VC[1], qf0[0], qf0[1], 0, sA_ + 1, acc0, lsum0);          \
    STEPTILE(KC[1], VC[1], qf1[0], qf1[1], 1, sA_ + 1, acc1, lsum1);          \
    __builtin_amdgcn_s_setprio(0);                                            \
    PAIR_SYNC();                                                              \
  } while (0)

  short8 KA[2][2], VA[2][2], KB[2][2], VB[2][2];

#if OCS_ASYNC
  SL_ISSUE(0); SL_ISSUE(1);
  __builtin_amdgcn_sched_barrier(0);
#endif
  LD_KV(KA[0], VA[0], NSX(0));
  LD_KV(KA[1], VA[1], NSX(1));
#if OCS_ASYNC
  __builtin_amdgcn_sched_barrier(0);
  asm volatile("s_waitcnt vmcnt(8)" ::: "memory");
  __builtin_amdgcn_s_barrier();
#endif

#pragma unroll
  for (int s = 0; s < NSTEPS; s += 4) {
    PAIR(s,     KA, VA, KB, VB);   // steps s,s+1; stage s+2,s+3
    PAIR(s + 2, KB, VB, KA, VA);   // steps s+2,s+3; stage s+4,s+5
  }
#undef PAIR
#undef STEPTILE
#undef TSB
#undef LD_KV
#undef CO_READ
#undef SL_ISSUE
#undef PAIR_SYNC
#undef NSX

  {
    float* pb0 = pacc + ((size_t)(c*1024 + wid0) * 4) * 256 + lane * 4;
    *(f32x4*)(pb0 + 0*256) = acc0[0][0];
    *(f32x4*)(pb0 + 1*256) = acc0[0][1];
    *(f32x4*)(pb0 + 2*256) = acc0[1][0];
    *(f32x4*)(pb0 + 3*256) = acc0[1][1];
    float* pb1 = pacc + ((size_t)(c*1024 + wid0 + 4) * 4) * 256 + lane * 4;
    *(f32x4*)(pb1 + 0*256) = acc1[0][0];
    *(f32x4*)(pb1 + 1*256) = acc1[0][1];
    *(f32x4*)(pb1 + 2*256) = acc1[1][0];
    *(f32x4*)(pb1 + 3*256) = acc1[1][1];
  }
#pragma unroll
  for (int ts = 0; ts < 2; ts++) {
    float L0 = lsum0[ts], L1 = lsum1[ts];
    L0 += __shfl_xor(L0, 16);  L0 += __shfl_xor(L0, 32);
    L1 += __shfl_xor(L1, 16);  L1 += __shfl_xor(L1, 32);
    if (g == 0) {
      pl[((size_t)(c*1024 + wid0)) * 32 + ts*16 + lt]     = L0;
      pl[((size_t)(c*1024 + wid0 + 4)) * 32 + ts*16 + lt] = L1;
    }
  }
}

// ---------------------------------------------------------------------------
// Combine partials across NS chunks, normalize, write vo; also accumulate
// per-row sum / sumsq (for the fused LN in gemm1) via one atomicAdd pair per
// row-segment after an in-wave shfl reduction over the 4 g-groups.
// ---------------------------------------------------------------------------
__global__ __launch_bounds__(256) void combine_kernel(
    const float* __restrict__ pacc, const float* __restrict__ pl,
    float* __restrict__ vo, float* __restrict__ rowsum,
    float* __restrict__ rowsumsq, int NS)
{
  const int lane = threadIdx.x & 63;
  const int wid = blockIdx.x * 4 + (threadIdx.x >> 6);
  const int b  = wid & 3;
  const int tt = (wid >> 2) & 31;
  const int h  = wid >> 7;
  const int t0 = tt * 32;
  const int lt = lane & 15, g = lane >> 4;

  f32x4 acc[4] = {};
  float L[2] = {0.f, 0.f};
  for (int cc = 0; cc < NS; ++cc) {
    const float* pb = pacc + ((size_t)(cc*1024 + wid) * 4) * 256 + lane * 4;
#pragma unroll
    for (int q = 0; q < 4; q++) {
      f32x4 v = *(const f32x4*)(pb + q * 256);
#pragma unroll
      for (int r = 0; r < 4; r++) acc[q][r] += v[r];
    }
    L[0] += pl[((size_t)(cc*1024 + wid)) * 32 + lt];
    L[1] += pl[((size_t)(cc*1024 + wid)) * 32 + 16 + lt];
  }
#pragma unroll
  for (int ts = 0; ts < 2; ts++) {
    const float inv = 1.0f / L[ts];
    const int t = t0 + ts*16 + lt;
    const int s = t >> 1, d = t & 1;
    const int row = b*512 + s;
    float* dst = vo + ((size_t)row * 512) + h*64 + d*32;
    float psum = 0.f, psq = 0.f;
#pragma unroll
    for (int vs = 0; vs < 2; vs++) {
      f32x4 o;
#pragma unroll
      for (int r = 0; r < 4; r++) {
        o[r] = acc[ts*2 + vs][r] * inv;
        psum += o[r];
        psq  += o[r] * o[r];
      }
      *(f32x4*)(dst + vs*16 + g*4) = o;
    }
    psum += __shfl_xor(psum, 16);  psum += __shfl_xor(psum, 32);
    psq  += __shfl_xor(psq, 16);   psq  += __shfl_xor(psq, 32);
    if (g == 0) {
      atomicAdd(&rowsum[row], psum);
      atomicAdd(&rowsumsq[row], psq);
    }
  }
}

// ---------------------------------------------------------------------------
extern "C" void kernel_launch(void* const* d_in, const int* in_sizes, int n_in,
                              void* d_out, int out_size, void* d_ws, size_t ws_size,
                              hipStream_t stream)
{
  const float* emb    = (const float*)d_in[0];
  const float* keys   = (const float*)d_in[1];
  const float* values = (const float*)d_in[2];
  const float* ocs    = (const float*)d_in[3];
  const float* Wq     = (const float*)d_in[4];
  const float* bq     = (const float*)d_in[5];
  const float* Wo     = (const float*)d_in[6];
  const float* bo     = (const float*)d_in[7];
  const float* gamma  = (const float*)d_in[8];
  const float* beta   = (const float*)d_in[9];

  char* ws = (char*)d_ws;
  ushort* qbf = (ushort*)(ws);                    // 2 MB  [b,h,t,ql] bf16
  ushort* kbf = (ushort*)(ws + (2u << 20));       // 4 MB  [b,h,n',ql] bf16 (permuted tiles)
  ushort* vbf = (ushort*)(ws + (6u << 20));       // 4 MB  [b,h,vl,n] bf16
  float*  vo  = (float*) (ws + (10u << 20));      // 4 MB  [m,512] f32
  const size_t pbase = (size_t)14u << 20;

  int NS;
  if      (ws_size >= ((size_t)31u << 20)) NS = 4;   // pacc 16MB + pl 0.5MB + stats
  else if (ws_size >= ((size_t)23u << 20)) NS = 2;
  else                                     NS = 1;
  float* pacc = (float*)(ws + pbase);                              // NS*4MB
  float* pl   = (float*)(ws + pbase + (size_t)NS * (4u << 20));    // NS*128KB
  float* rsum = (float*)(ws + pbase + (size_t)NS * (4u << 20) + (size_t)NS * (128u << 10));
  float* rsq  = rsum + 2048;

  prep_gemm0<<<dim3(516), dim3(256), 0, stream>>>(keys, values, kbf, vbf,
                                                  emb, Wq, bq, qbf, rsum);
  if (NS == 4)
    attn_kernel<16><<<dim3(512), dim3(256), 0, stream>>>(qbf, kbf, vbf, ocs, pacc, pl);
  else if (NS == 2)
    attn_kernel<32><<<dim3(256), dim3(256), 0, stream>>>(qbf, kbf, vbf, ocs, pacc, pl);
  else
    attn_kernel<64><<<dim3(128), dim3(256), 0, stream>>>(qbf, kbf, vbf, ocs, pacc, pl);
  combine_kernel<<<dim3(256), dim3(256), 0, stream>>>(pacc, pl, vo, rsum, rsq, NS);
  gemm1_ln<<<dim3(32, 16), dim3(256), 0, stream>>>(vo, Wo, bo, (float*)d_out,
                                                   rsum, rsq, gamma, beta);
}

// Round 20
// 80.041 us; speedup vs baseline: 1.0993x; 1.0993x over previous
//
#include <hip/hip_runtime.h>
#include <hip/hip_bf16.h>

// Problem constants: B=4, S=512, N=2048, E=1024, QL=32, H=8, D=2, VL=32
// Inputs: 0 embeddings[4,512,1024] 1 keys[4,2048,256] 2 values[4,2048,256]
//         3 ocs[8,1024,2048] 4 Wq[512,1024] 5 bq[512] 6 Wo[1024,512] 7 bo[1024]
//         8 gamma[512] 9 beta[512]       all float32.  Output [4,512,1024] f32.

typedef short  short8 __attribute__((ext_vector_type(8)));
typedef float  f32x4  __attribute__((ext_vector_type(4)));

__device__ __forceinline__ ushort f2bf(float x) {
  union { float f; unsigned int u; } v; v.f = x;
  unsigned int r = v.u + 0x7fffu + ((v.u >> 16) & 1u);
  return (ushort)(r >> 16);
}

// hardware packed f32x2 -> bf16x2 (RNE), 1 instr. Used ONLY where the
// consumer is a DS/shuffle/store op (never directly feeding MFMA).
__device__ __forceinline__ unsigned int cvtpk(float a, float b) {
  unsigned int r;
  asm("v_cvt_pk_bf16_f32 %0, %1, %2" : "=v"(r) : "v"(a), "v"(b));
  return r;
}
__device__ __forceinline__ short8 cvt8(f32x4 a, f32x4 b) {
  union { unsigned int u[4]; short8 s; } r;
  r.u[0] = cvtpk(a[0], a[1]);
  r.u[1] = cvtpk(a[2], a[3]);
  r.u[2] = cvtpk(b[0], b[1]);
  r.u[3] = cvtpk(b[2], b[3]);
  return r.s;
}

#if __has_builtin(__builtin_amdgcn_global_load_lds)
#define OCS_ASYNC 1
__device__ __forceinline__ void gl_lds16(const float* g, float* l) {
  __builtin_amdgcn_global_load_lds(
      (const __attribute__((address_space(1))) unsigned int*)g,
      (__attribute__((address_space(3))) unsigned int*)l, 16, 0, 0);
}
#else
#define OCS_ASYNC 0
#endif

// ---------------------------------------------------------------------------
// prep body: keys[b,n,ql*8+h] -> kbf[b,h,n',ql] (permuted tiles: position
// p = 16s+4gg+r holds source row 8gg+4s+r, so QK^T output lands directly in
// the K=32 PV B-fragment order); values -> vbf[b,h,vl,n].
// ---------------------------------------------------------------------------
__device__ __forceinline__ void prep_body(
    char* smem, int bi,
    const float* __restrict__ keys, const float* __restrict__ values,
    ushort* __restrict__ kbf, ushort* __restrict__ vbf)
{
  ushort (*T)[264] = (ushort (*)[264])smem;    // [32][264]
  const int b  = bi >> 6;
  const int n0 = (bi & 63) * 32;
  const int t  = threadIdx.x;
  const int nr = t >> 3;                // 0..31
  const int c0 = (t & 7) * 32;          // 0..224

  {
    const float* src = keys + ((size_t)b*2048 + n0 + nr)*256 + c0;
#pragma unroll
    for (int j = 0; j < 32; j += 8) {
      f32x4 x0 = *(const f32x4*)(src + j);
      f32x4 x1 = *(const f32x4*)(src + j + 4);
      *(short8*)&T[nr][c0 + j] = cvt8(x0, x1);
    }
  }
  __syncthreads();
  {
    const int h = t >> 5, nn = t & 31;
    const int pp = 16*((nn >> 2) & 1) + 4*(nn >> 3) + (nn & 3);
    ushort* dst = kbf + (((size_t)(b*8 + h) * 2048) + n0 + pp) * 32;
#pragma unroll
    for (int j = 0; j < 4; j++) {
      short8 w;
#pragma unroll
      for (int i = 0; i < 8; i++) w[i] = (short)T[nn][(j*8 + i)*8 + h];
      *(short8*)(dst + j*8) = w;
    }
  }
  __syncthreads();
  {
    const float* src = values + ((size_t)b*2048 + n0 + nr)*256 + c0;
#pragma unroll
    for (int j = 0; j < 32; j += 8) {
      f32x4 x0 = *(const f32x4*)(src + j);
      f32x4 x1 = *(const f32x4*)(src + j + 4);
      *(short8*)&T[nr][c0 + j] = cvt8(x0, x1);
    }
  }
  __syncthreads();
  {
    const int c = t, h = c & 7, vl = c >> 3;
    ushort* dst = vbf + (((size_t)(b*8 + h) * 32) + vl) * 2048 + n0;
#pragma unroll
    for (int j = 0; j < 4; j++) {
      short8 w;
#pragma unroll
      for (int i = 0; i < 8; i++) w[i] = (short)T[j*8 + i][c];
      *(short8*)(dst + j*8) = w;
    }
  }
}

// ---------------------------------------------------------------------------
// GEMM body (NT): out[m,n] = sum_k A'[m,k]*B[n,k] + bias[n]. 64x64 tile,
// 4 waves, R15-proven pipeline: double-buffered LDS, prefetch distance 1,
// raw s_barrier (no vmcnt drain), lgkmcnt(0) before write-side barrier.
// EPI=0: A'=A; scatter-store bf16*(1/sqrt32) into qbf.
// EPI=1: A'[m,k] = (A[m,k]-mean[m])*rstd[m]*gamma[k]+beta[k], stats from
//        per-row sum/sumsq (combine's atomics); f32 row-major out.
// ---------------------------------------------------------------------------
template<int EPI>
__device__ __forceinline__ void gemm_body(
    char* smem,
    const float* __restrict__ A, const float* __restrict__ Bm,
    const float* __restrict__ bias, void* __restrict__ outp,
    int M, int N, int K, int m0, int n0,
    const float* __restrict__ rowsum, const float* __restrict__ rowsumsq,
    const float* __restrict__ gamma,  const float* __restrict__ beta)
{
  ushort* As = (ushort*)smem;            // [2][64][32]
  ushort* Bs = (ushort*)(smem + 8192);   // [2][64][32]
  const int tid = threadIdx.x;
  const int lane = tid & 63;
  const int wid  = tid >> 6;
  const int wm = wid >> 1, wn = wid & 1;
  const int lt = lane & 15, g = lane >> 4;
  const int lrow = tid >> 2;      // 0..63
  const int lseg = tid & 3;       // 0..3 (8 floats each)
  const int slot_w = lseg ^ ((lrow & 3) ^ ((lrow >> 2) & 3));

  f32x4 acc[2][2] = {};
  f32x4 pa0, pa1, pb0, pb1;     // named prefetch registers

  float mean_r = 0.f, rstd_r = 1.f;
  if (EPI == 1) {
    const float s_  = rowsum[m0 + lrow];
    const float sq_ = rowsumsq[m0 + lrow];
    mean_r = s_ * (1.0f/512.0f);
    rstd_r = rsqrtf(sq_ * (1.0f/512.0f) - mean_r * mean_r + 1e-5f);
  }

#define GLOAD(K0) do {                                                        \
    const float* sa_ = A  + (size_t)(m0 + lrow) * K + (K0) + lseg * 8;        \
    pa0 = *(const f32x4*)sa_;  pa1 = *(const f32x4*)(sa_ + 4);                \
    const float* sb_ = Bm + (size_t)(n0 + lrow) * K + (K0) + lseg * 8;        \
    pb0 = *(const f32x4*)sb_;  pb1 = *(const f32x4*)(sb_ + 4);                \
  } while (0)
#define SWRITE(BUF, K0) do {                                                  \
    f32x4 qa0 = pa0, qa1 = pa1;                                               \
    if (EPI == 1) {                                                           \
      const float* gp_ = gamma + (K0) + lseg * 8;                             \
      const float* bp_ = beta  + (K0) + lseg * 8;                             \
      f32x4 g0_ = *(const f32x4*)gp_, g1_ = *(const f32x4*)(gp_ + 4);         \
      f32x4 b0_ = *(const f32x4*)bp_, b1_ = *(const f32x4*)(bp_ + 4);         \
      _Pragma("unroll")                                                       \
      for (int r_ = 0; r_ < 4; r_++) {                                        \
        qa0[r_] = (qa0[r_] - mean_r) * rstd_r * g0_[r_] + b0_[r_];            \
        qa1[r_] = (qa1[r_] - mean_r) * rstd_r * g1_[r_] + b1_[r_];            \
      }                                                                       \
    }                                                                         \
    *(short8*)&As[(BUF)*2048 + lrow*32 + slot_w * 8] = cvt8(qa0, qa1);        \
    *(short8*)&Bs[(BUF)*2048 + lrow*32 + slot_w * 8] = cvt8(pb0, pb1);        \
  } while (0)

  // prologue: stage k=0 into buf 0 (full drain once is fine)
  GLOAD(0);
  SWRITE(0, 0);
  __syncthreads();

  int cur = 0;
  for (int k0 = 0; k0 < K; k0 += 32) {
    const bool more = (k0 + 32 < K);
    if (more) GLOAD(k0 + 32);          // in flight across barrier1
    short8 af[2], bfr[2];
#pragma unroll
    for (int ss = 0; ss < 2; ss++) {
      const int ra = wm*32 + ss*16 + lt;
      af[ss]  = *(const short8*)&As[cur*2048 + ra*32 + (g ^ ((ra & 3) ^ ((ra >> 2) & 3))) * 8];
      const int rb = wn*32 + ss*16 + lt;
      bfr[ss] = *(const short8*)&Bs[cur*2048 + rb*32 + (g ^ ((rb & 3) ^ ((rb >> 2) & 3))) * 8];
    }
#pragma unroll
    for (int i = 0; i < 2; i++)
#pragma unroll
      for (int j = 0; j < 2; j++)
        acc[i][j] = __builtin_amdgcn_mfma_f32_16x16x32_bf16(af[i], bfr[j], acc[i][j], 0, 0, 0);
    asm volatile("s_barrier" ::: "memory");
    if (more) {
      SWRITE(cur ^ 1, k0 + 32);
      asm volatile("s_waitcnt lgkmcnt(0)" ::: "memory");
    }
    asm volatile("s_barrier" ::: "memory");
    cur ^= 1;
  }

#pragma unroll
  for (int i = 0; i < 2; i++)
#pragma unroll
    for (int j = 0; j < 2; j++) {
      const int n  = n0 + wn*32 + j*16 + lt;
      const float bv = bias[n];
      const int mb = m0 + wm*32 + i*16 + g*4;
#pragma unroll
      for (int r = 0; r < 4; r++) {
        const int mm = mb + r;
        if (EPI == 0) {
          const float val = (acc[i][j][r] + bv) * 0.17677669529663687f;
          const int bb = mm >> 9, s = mm & 511;
          const int d = n >> 8, ql = (n >> 3) & 31, hh = n & 7;
          const int tt = s*2 + d;
          ((ushort*)outp)[((size_t)(bb*8 + hh) * 1024 + tt) * 32 + ql] = f2bf(val);
        } else {
          ((float*)outp)[(size_t)mm * N + n] = acc[i][j][r] + bv;
        }
      }
    }
#undef GLOAD
#undef SWRITE
}

// ---------------------------------------------------------------------------
// Fused dispatch 1: blocks 0..255 prep; 256..511 gemm0; 512..515 zero the
// LN stats accumulators (replaces a hipMemsetAsync graph node).
// ---------------------------------------------------------------------------
__global__ __launch_bounds__(256) void prep_gemm0(
    const float* __restrict__ keys, const float* __restrict__ values,
    ushort* __restrict__ kbf, ushort* __restrict__ vbf,
    const float* __restrict__ emb, const float* __restrict__ Wq,
    const float* __restrict__ bq, ushort* __restrict__ qbf,
    float* __restrict__ stats)   // 4096 floats: rsum[2048] ++ rsq[2048]
{
  __shared__ __align__(16) char smem[17408];
  const int bi = blockIdx.x;
  if (bi < 256) {
    prep_body(smem, bi, keys, values, kbf, vbf);
  } else if (bi < 512) {
    const int gblk = bi - 256;           // 0..255 -> (mt 0..31, nt 0..7)
    const int m0 = (gblk & 31) * 64;
    const int n0 = (gblk >> 5) * 64;
    gemm_body<0>(smem, emb, Wq, bq, (void*)qbf, 2048, 512, 1024, m0, n0,
                 nullptr, nullptr, nullptr, nullptr);
  } else {
    stats[(bi - 512) * 1024 + threadIdx.x * 4 + 0] = 0.f;
    stats[(bi - 512) * 1024 + threadIdx.x * 4 + 1] = 0.f;
    stats[(bi - 512) * 1024 + threadIdx.x * 4 + 2] = 0.f;
    stats[(bi - 512) * 1024 + threadIdx.x * 4 + 3] = 0.f;
  }
}

// ---------------------------------------------------------------------------
// gemm1 with fused LayerNorm on A (stats derived from combine's atomics).
// ---------------------------------------------------------------------------
__global__ __launch_bounds__(256) void gemm1_ln(
    const float* __restrict__ vo, const float* __restrict__ Wo,
    const float* __restrict__ bo, float* __restrict__ outp,
    const float* __restrict__ rowsum, const float* __restrict__ rowsumsq,
    const float* __restrict__ gamma, const float* __restrict__ beta)
{
  __shared__ __align__(16) char smem[16384];
  gemm_body<1>(smem, vo, Wo, bo, (void*)outp, 2048, 1024, 512,
               blockIdx.x * 64, blockIdx.y * 64, rowsum, rowsumsq, gamma, beta);
}

// ---------------------------------------------------------------------------
// Attention (split-n), t-PAIR per wave. R18 body verbatim (runtime nsteps,
// VGPR ~112): 4-buffer LDS ocs ring (32KB), per pair [4 DMA then 8 K/V]
// pinned, pair-end vmcnt(8) retires exactly the 4 DMAs. Launched at NS=4.
// ---------------------------------------------------------------------------
__global__ __launch_bounds__(256) void attn_kernel(
    const ushort* __restrict__ qbf, const ushort* __restrict__ kbf,
    const ushort* __restrict__ vbf, const float* __restrict__ ocs,
    float* __restrict__ pacc, float* __restrict__ pl, int nsteps)
{
#if OCS_ASYNC
  __shared__ float obuf[4][2048];   // ring: 4 x [2 tiles][32 rows][8 slots][4 f32]
#endif
  const int tid  = threadIdx.x;
  const int lane = tid & 63;
  const int id = blockIdx.x;
  const int h   = id & 7;
  const int ttp = (id >> 3) & 15;
  const int c   = id >> 7;
  const int b  = tid >> 6;
  const int wid0 = ((h << 5) + 2*ttp) * 4 + b;   // tile0's wid; tile1 = wid0+4
  const int t0 = ttp * 64;
  const int lt = lane & 15, g = lane >> 4;
  const int n_start = c * nsteps * 32;

  const ushort* qp = qbf + (size_t)(b*8 + h) * (1024*32);
  const ushort* kp = kbf + (size_t)(b*8 + h) * (2048*32);
  const ushort* vp = vbf + (size_t)(b*8 + h) * (32*2048);
  const float*  op = ocs + (size_t)h * (1024*2048);

#define NSX(I) (((I) < nsteps) ? (n_start + (I)*32) : n_start)

  const int srow = tid >> 3;
  const int scol = 4 * ((tid & 7) ^ (srow & 7));
  const float* sb0 = op + (size_t)(t0 + srow) * 2048 + scol;
  const float* sb1 = op + (size_t)(t0 + 32 + srow) * 2048 + scol;
#if OCS_ASYNC
  const int ldsw = (tid & 192) * 16;   // per-wave LDS byte base (lane*16 added by HW)
#define SL_ISSUE(STEP) do {                                                   \
    gl_lds16(sb0 + NSX(STEP), (float*)((char*)obuf + (((STEP) & 3) << 13) + ldsw));        \
    gl_lds16(sb1 + NSX(STEP), (float*)((char*)obuf + (((STEP) & 3) << 13) + 4096 + ldsw)); \
  } while (0)
  const int ro0 = lt * 128;            // ts=0 row byte offset
  const int ro1 = (16 + lt) * 128;     // ts=1
  const int c0x = ((2*g)     ^ (lt & 7)) * 16;   // sc0 slot bytes
  const int c1x = ((2*g + 1) ^ (lt & 7)) * 16;   // sc1 slot bytes
#define CO_READ(DST, TILE, STEP) do {                                         \
    const char* bb_ = (const char*)obuf + (((STEP) & 3) << 13) + ((TILE) << 12); \
    DST[0][0] = *(const f32x4*)(bb_ + ro0 + c0x);                             \
    DST[1][0] = *(const f32x4*)(bb_ + ro0 + c1x);                             \
    DST[0][1] = *(const f32x4*)(bb_ + ro1 + c0x);                             \
    DST[1][1] = *(const f32x4*)(bb_ + ro1 + c1x);                             \
  } while (0)
#define PAIR_SYNC() do {                                                      \
    __builtin_amdgcn_sched_barrier(0);                                        \
    asm volatile("s_waitcnt vmcnt(8)" ::: "memory");                          \
    __builtin_amdgcn_sched_barrier(0);                                        \
    __builtin_amdgcn_s_barrier();                                             \
  } while (0)
#else
#define SL_ISSUE(STEP)
#define CO_READ(DST, TILE, STEP) do {                                         \
    const int nn_ = NSX(STEP);                                                \
    const float* r0_ = op + (size_t)(t0 + (TILE)*32 + lt) * 2048 + nn_;       \
    const float* r1_ = op + (size_t)(t0 + (TILE)*32 + 16 + lt) * 2048 + nn_;  \
    DST[0][0] = *(const f32x4*)(r0_ + 8*g);                                   \
    DST[1][0] = *(const f32x4*)(r0_ + 8*g + 4);                               \
    DST[0][1] = *(const f32x4*)(r1_ + 8*g);                                   \
    DST[1][1] = *(const f32x4*)(r1_ + 8*g + 4);                               \
  } while (0)
#define PAIR_SYNC()
#endif

#define LD_KV(KD, VD, NN) do {                                                \
    KD[0] = *(const short8*)(kp + (size_t)((NN) + lt) * 32 + g*8);            \
    KD[1] = *(const short8*)(kp + (size_t)((NN) + 16 + lt) * 32 + g*8);       \
    VD[0] = *(const short8*)(vp + (size_t)lt * 2048 + (NN) + g*8);            \
    VD[1] = *(const short8*)(vp + (size_t)(16 + lt) * 2048 + (NN) + g*8);     \
  } while (0)

  short8 qf0[2], qf1[2];
#pragma unroll
  for (int ts = 0; ts < 2; ts++) {
    qf0[ts] = *(const short8*)(qp + (t0 + ts*16 + lt)*32 + g*8);
    qf1[ts] = *(const short8*)(qp + (t0 + 32 + ts*16 + lt)*32 + g*8);
  }

  f32x4 acc0[2][2] = {}, acc1[2][2] = {};
  float lsum0[2] = {0.f, 0.f}, lsum1[2] = {0.f, 0.f};
  const f32x4 fzero = {0.f, 0.f, 0.f, 0.f};

#define TSB(SC0, SC1, CO0, CO1, VLO, VHI, LS, ACCA, ACCB) do {                \
    float p0 = __expf(SC0[0] - CO0[0]);                                       \
    float p1 = __expf(SC0[1] - CO0[1]);                                       \
    float p2 = __expf(SC0[2] - CO0[2]);                                       \
    float p3 = __expf(SC0[3] - CO0[3]);                                       \
    float p4 = __expf(SC1[0] - CO1[0]);                                       \
    float p5 = __expf(SC1[1] - CO1[1]);                                       \
    float p6 = __expf(SC1[2] - CO1[2]);                                       \
    float p7 = __expf(SC1[3] - CO1[3]);                                       \
    LS += ((p0+p1)+(p2+p3)) + ((p4+p5)+(p6+p7));                              \
    union { unsigned int u[4]; short8 s; } pf;                                \
    pf.u[0] = (unsigned int)f2bf(p0) | ((unsigned int)f2bf(p1) << 16);        \
    pf.u[1] = (unsigned int)f2bf(p2) | ((unsigned int)f2bf(p3) << 16);        \
    pf.u[2] = (unsigned int)f2bf(p4) | ((unsigned int)f2bf(p5) << 16);        \
    pf.u[3] = (unsigned int)f2bf(p6) | ((unsigned int)f2bf(p7) << 16);        \
    ACCA = __builtin_amdgcn_mfma_f32_16x16x32_bf16(VLO, pf.s, ACCA, 0, 0, 0); \
    ACCB = __builtin_amdgcn_mfma_f32_16x16x32_bf16(VHI, pf.s, ACCB, 0, 0, 0); \
  } while (0)

#define STEPTILE(KC_, VC_, QFA, QFB, TILE, STEP, ACC, LS) do {                \
    f32x4 s0a = __builtin_amdgcn_mfma_f32_16x16x32_bf16(KC_[0], QFA, fzero, 0, 0, 0); \
    f32x4 s1a = __builtin_amdgcn_mfma_f32_16x16x32_bf16(KC_[1], QFA, fzero, 0, 0, 0); \
    f32x4 s0b = __builtin_amdgcn_mfma_f32_16x16x32_bf16(KC_[0], QFB, fzero, 0, 0, 0); \
    f32x4 s1b = __builtin_amdgcn_mfma_f32_16x16x32_bf16(KC_[1], QFB, fzero, 0, 0, 0); \
    f32x4 co[2][2];                                                           \
    CO_READ(co, TILE, STEP);                                                  \
    TSB(s0a, s1a, co[0][0], co[1][0], VC_[0], VC_[1], LS[0], ACC[0][0], ACC[0][1]); \
    TSB(s0b, s1b, co[0][1], co[1][1], VC_[0], VC_[1], LS[1], ACC[1][0], ACC[1][1]); \
  } while (0)

#define PAIR(SA_, KC, VC, KN, VN) do {                                        \
    const int sA_ = (SA_);                                                    \
    SL_ISSUE(sA_ + 2);                                                        \
    SL_ISSUE(sA_ + 3);                                                        \
    __builtin_amdgcn_sched_barrier(0);                                        \
    LD_KV(KN[0], VN[0], NSX(sA_ + 2));                                        \
    LD_KV(KN[1], VN[1], NSX(sA_ + 3));                                        \
    __builtin_amdgcn_sched_barrier(0);                                        \
    STEPTILE(KC[0], VC[0], qf0[0], qf0[1], 0, sA_,     acc0, lsum0);          \
    STEPTILE(KC[0], VC[0], qf1[0], qf1[1], 1, sA_,     acc1, lsum1);          \
    STEPTILE(KC[1], VC[1], qf0[0], qf0[1], 0, sA_ + 1, acc0, lsum0);          \
    STEPTILE(KC[1], VC[1], qf1[0], qf1[1], 1, sA_ + 1, acc1, lsum1);          \
    PAIR_SYNC();                                                              \
  } while (0)

  short8 KA[2][2], VA[2][2], KB[2][2], VB[2][2];

#if OCS_ASYNC
  SL_ISSUE(0); SL_ISSUE(1);
  __builtin_amdgcn_sched_barrier(0);
#endif
  LD_KV(KA[0], VA[0], NSX(0));
  LD_KV(KA[1], VA[1], NSX(1));
#if OCS_ASYNC
  __builtin_amdgcn_sched_barrier(0);
  asm volatile("s_waitcnt vmcnt(8)" ::: "memory");
  __builtin_amdgcn_s_barrier();
#endif

  for (int s = 0; s < nsteps; s += 4) {
    PAIR(s,     KA, VA, KB, VB);   // steps s,s+1; stage s+2,s+3
    PAIR(s + 2, KB, VB, KA, VA);   // steps s+2,s+3; stage s+4,s+5
  }
#undef PAIR
#undef STEPTILE
#undef TSB
#undef LD_KV
#undef CO_READ
#undef SL_ISSUE
#undef PAIR_SYNC
#undef NSX

  {
    float* pb0 = pacc + ((size_t)(c*1024 + wid0) * 4) * 256 + lane * 4;
    *(f32x4*)(pb0 + 0*256) = acc0[0][0];
    *(f32x4*)(pb0 + 1*256) = acc0[0][1];
    *(f32x4*)(pb0 + 2*256) = acc0[1][0];
    *(f32x4*)(pb0 + 3*256) = acc0[1][1];
    float* pb1 = pacc + ((size_t)(c*1024 + wid0 + 4) * 4) * 256 + lane * 4;
    *(f32x4*)(pb1 + 0*256) = acc1[0][0];
    *(f32x4*)(pb1 + 1*256) = acc1[0][1];
    *(f32x4*)(pb1 + 2*256) = acc1[1][0];
    *(f32x4*)(pb1 + 3*256) = acc1[1][1];
  }
#pragma unroll
  for (int ts = 0; ts < 2; ts++) {
    float L0 = lsum0[ts], L1 = lsum1[ts];
    L0 += __shfl_xor(L0, 16);  L0 += __shfl_xor(L0, 32);
    L1 += __shfl_xor(L1, 16);  L1 += __shfl_xor(L1, 32);
    if (g == 0) {
      pl[((size_t)(c*1024 + wid0)) * 32 + ts*16 + lt]     = L0;
      pl[((size_t)(c*1024 + wid0 + 4)) * 32 + ts*16 + lt] = L1;
    }
  }
}

// ---------------------------------------------------------------------------
// Combine partials across NS chunks, normalize, write vo; also accumulate
// per-row sum / sumsq (for the fused LN in gemm1) via one atomicAdd pair per
// row-segment after an in-wave shfl reduction over the 4 g-groups.
// ---------------------------------------------------------------------------
__global__ __launch_bounds__(256) void combine_kernel(
    const float* __restrict__ pacc, const float* __restrict__ pl,
    float* __restrict__ vo, float* __restrict__ rowsum,
    float* __restrict__ rowsumsq, int NS)
{
  const int lane = threadIdx.x & 63;
  const int wid = blockIdx.x * 4 + (threadIdx.x >> 6);
  const int b  = wid & 3;
  const int tt = (wid >> 2) & 31;
  const int h  = wid >> 7;
  const int t0 = tt * 32;
  const int lt = lane & 15, g = lane >> 4;

  f32x4 acc[4] = {};
  float L[2] = {0.f, 0.f};
  for (int cc = 0; cc < NS; ++cc) {
    const float* pb = pacc + ((size_t)(cc*1024 + wid) * 4) * 256 + lane * 4;
#pragma unroll
    for (int q = 0; q < 4; q++) {
      f32x4 v = *(const f32x4*)(pb + q * 256);
#pragma unroll
      for (int r = 0; r < 4; r++) acc[q][r] += v[r];
    }
    L[0] += pl[((size_t)(cc*1024 + wid)) * 32 + lt];
    L[1] += pl[((size_t)(cc*1024 + wid)) * 32 + 16 + lt];
  }
#pragma unroll
  for (int ts = 0; ts < 2; ts++) {
    const float inv = 1.0f / L[ts];
    const int t = t0 + ts*16 + lt;
    const int s = t >> 1, d = t & 1;
    const int row = b*512 + s;
    float* dst = vo + ((size_t)row * 512) + h*64 + d*32;
    float psum = 0.f, psq = 0.f;
#pragma unroll
    for (int vs = 0; vs < 2; vs++) {
      f32x4 o;
#pragma unroll
      for (int r = 0; r < 4; r++) {
        o[r] = acc[ts*2 + vs][r] * inv;
        psum += o[r];
        psq  += o[r] * o[r];
      }
      *(f32x4*)(dst + vs*16 + g*4) = o;
    }
    psum += __shfl_xor(psum, 16);  psum += __shfl_xor(psum, 32);
    psq  += __shfl_xor(psq, 16);   psq  += __shfl_xor(psq, 32);
    if (g == 0) {
      atomicAdd(&rowsum[row], psum);
      atomicAdd(&rowsumsq[row], psq);
    }
  }
}

// ---------------------------------------------------------------------------
extern "C" void kernel_launch(void* const* d_in, const int* in_sizes, int n_in,
                              void* d_out, int out_size, void* d_ws, size_t ws_size,
                              hipStream_t stream)
{
  const float* emb    = (const float*)d_in[0];
  const float* keys   = (const float*)d_in[1];
  const float* values = (const float*)d_in[2];
  const float* ocs    = (const float*)d_in[3];
  const float* Wq     = (const float*)d_in[4];
  const float* bq     = (const float*)d_in[5];
  const float* Wo     = (const float*)d_in[6];
  const float* bo     = (const float*)d_in[7];
  const float* gamma  = (const float*)d_in[8];
  const float* beta   = (const float*)d_in[9];

  char* ws = (char*)d_ws;
  ushort* qbf = (ushort*)(ws);                    // 2 MB  [b,h,t,ql] bf16
  ushort* kbf = (ushort*)(ws + (2u << 20));       // 4 MB  [b,h,n',ql] bf16 (permuted tiles)
  ushort* vbf = (ushort*)(ws + (6u << 20));       // 4 MB  [b,h,vl,n] bf16
  float*  vo  = (float*) (ws + (10u << 20));      // 4 MB  [m,512] f32
  const size_t pbase = (size_t)14u << 20;

  int NS;
  if      (ws_size >= ((size_t)31u << 20)) NS = 4;   // pacc 16MB + pl 0.5MB + stats
  else if (ws_size >= ((size_t)23u << 20)) NS = 2;
  else                                     NS = 1;
  float* pacc = (float*)(ws + pbase);                              // NS*4MB
  float* pl   = (float*)(ws + pbase + (size_t)NS * (4u << 20));    // NS*128KB
  float* rsum = (float*)(ws + pbase + (size_t)NS * (4u << 20) + (size_t)NS * (128u << 10));
  float* rsq  = rsum + 2048;
  const int nsteps = 2048 / (NS * 32);

  prep_gemm0<<<dim3(516), dim3(256), 0, stream>>>(keys, values, kbf, vbf,
                                                  emb, Wq, bq, qbf, rsum);
  attn_kernel<<<dim3(128 * NS), dim3(256), 0, stream>>>(qbf, kbf, vbf, ocs, pacc, pl, nsteps);
  combine_kernel<<<dim3(256), dim3(256), 0, stream>>>(pacc, pl, vo, rsum, rsq, NS);
  gemm1_ln<<<dim3(32, 16), dim3(256), 0, stream>>>(vo, Wo, bo, (float*)d_out,
                                                   rsum, rsq, gamma, beta);
}